// Round 15
// baseline (1617.239 us; speedup 1.0000x reference)
//
#include <hip/hip_runtime.h>
#include <hip/hip_bf16.h>

typedef __hip_bfloat16 bf16;
typedef __attribute__((ext_vector_type(8))) short s16x8;
typedef __attribute__((ext_vector_type(4))) float f32x4;
typedef __attribute__((ext_vector_type(2))) float f32x2;

#define B_TOT 1024
#define T_LEN 256
#define H_DIM 256
#define PRED_LEN 16

__device__ __forceinline__ float b2f(short u) {
  union { unsigned int i; float f; } c;
  c.i = ((unsigned int)(unsigned short)u) << 16;
  return c.f;
}
__device__ __forceinline__ float fsig(float x) {
  return __builtin_amdgcn_rcpf(1.f + __expf(-x));
}
__device__ __forceinline__ float ftanh(float x) {
  return 1.f - 2.f * __builtin_amdgcn_rcpf(1.f + __expf(2.f * x));
}
__device__ __forceinline__ f32x4 mfma16(s16x8 a, s16x8 b, f32x4 c) {
  return __builtin_amdgcn_mfma_f32_16x16x32_bf16(a, b, c, 0, 0, 0);
}
template <int HI>
__device__ __forceinline__ f32x2 fp8pk2f(unsigned int pk) {
  return __builtin_amdgcn_cvt_pk_f32_fp8(pk, HI);
}
__device__ __forceinline__ unsigned char f2fp8(float v) {
  return (unsigned char)(__builtin_amdgcn_cvt_pk_fp8_f32(v, v, 0, 0) & 0xff);
}
__device__ __forceinline__ uint2 pk8fp8(s16x8 hv) {
  unsigned int lo = 0, hi = 0;
  lo = __builtin_amdgcn_cvt_pk_fp8_f32(b2f(hv[0]), b2f(hv[1]), lo, 0);
  lo = __builtin_amdgcn_cvt_pk_fp8_f32(b2f(hv[2]), b2f(hv[3]), lo, 1);
  hi = __builtin_amdgcn_cvt_pk_fp8_f32(b2f(hv[4]), b2f(hv[5]), hi, 0);
  hi = __builtin_amdgcn_cvt_pk_fp8_f32(b2f(hv[6]), b2f(hv[7]), hi, 1);
  uint2 w; w.x = lo; w.y = hi; return w;
}

// ---------- Kernel 0: pack fp32 weights -> bf16 ws layouts ------------------
// wtEncF and wtDec PRE-SCALED by 2 (ep8 = 2*enc_proj, q = 2*q_orig) for the
// restructured tanh in decoder phase 2.
__global__ __launch_bounds__(256) void convert_kernel(
    const float* __restrict__ eWhh, const float* __restrict__ Wt,
    const float* __restrict__ dWhh, const float* __restrict__ dWih,
    bf16* __restrict__ encWF, bf16* __restrict__ wtEncF,
    bf16* __restrict__ wtDec, bf16* __restrict__ whhD, bf16* __restrict__ wihPD)
{
  int i = blockIdx.x*256 + threadIdx.x;
  if (i < 24576) {           // encWF fragment slots
    int l = i & 63, kc = (i>>6)&7, tile = i>>9;
    int j = tile*16 + (l&15);
    int k = kc*32 + ((l>>4)&3)*8;
    #pragma unroll
    for (int e = 0; e < 8; ++e)
      encWF[i*8+e] = __float2bfloat16(eWhh[j*256 + k + e]);
  } else if (i < 32768) {    // wtEncF fragment slots (x2 scale)
    int s = i - 24576;
    int l = s & 63, kc = (s>>6)&7, tile = s>>9;
    int j = tile*16 + (l&15);
    int k = kc*32 + ((l>>4)&3)*8;
    #pragma unroll
    for (int e = 0; e < 8; ++e)
      wtEncF[s*8+e] = __float2bfloat16(2.f * Wt[j*512 + 256 + k + e]);
  }
  if (i < 768*288) {
    int g = i / 288, k = i - g*288;
    wihPD[i] = __float2bfloat16((k < 265) ? dWih[g*265 + k] : 0.f);
  }
  if (i < 256*256) {         // wtDec (x2 scale)
    int g = i >> 8, k = i & 255;
    wtDec[i] = __float2bfloat16(2.f * Wt[g*512 + k]);
  }
  if (i < 768*256) whhD[i] = __float2bfloat16(dWhh[i]);
}

// ---------- Kernel 1: agent attention (tanh restructured) ------------------
__global__ __launch_bounds__(256) void agent_attn_kernel(
    const float* __restrict__ x, const float* __restrict__ Wa,
    const float* __restrict__ ba, const float* __restrict__ va,
    float* __restrict__ treprs)
{
  __shared__ float w0[256], w1[256], w2[256], baL[256], vaL[256];
  __shared__ float halfVsum;
  int tid = threadIdx.x;
  w0[tid] = 2.f * Wa[tid*3+0];
  w1[tid] = 2.f * Wa[tid*3+1];
  w2[tid] = 2.f * Wa[tid*3+2];
  baL[tid] = 2.f * ba[tid];
  vaL[tid] = 2.f * va[tid];
  __syncthreads();
  if (tid == 0) {
    float s = 0.f;
    for (int i = 0; i < 256; ++i) s += vaL[i];
    halfVsum = 0.25f * s;      // = 0.5 * sum(va) ... vaL = 2*va
  }
  __syncthreads();
  long idx = (long)blockIdx.x * 256 + tid;
  float xa[9];
  #pragma unroll
  for (int i = 0; i < 9; ++i) xa[i] = x[idx*9 + i];
  float s0 = 0.f, s1 = 0.f, s2 = 0.f;
  for (int h = 0; h < 256; ++h) {
    float a0 = w0[h], a1 = w1[h], a2 = w2[h], bb = baL[h], vv = vaL[h];
    s0 += vv * __builtin_amdgcn_rcpf(1.f + __expf(a0*xa[0] + a1*xa[1] + a2*xa[2] + bb));
    s1 += vv * __builtin_amdgcn_rcpf(1.f + __expf(a0*xa[3] + a1*xa[4] + a2*xa[5] + bb));
    s2 += vv * __builtin_amdgcn_rcpf(1.f + __expf(a0*xa[6] + a1*xa[7] + a2*xa[8] + bb));
  }
  float vs = 2.f * halfVsum;
  s0 = vs - s0; s1 = vs - s1; s2 = vs - s2;
  float mx = fmaxf(s0, fmaxf(s1, s2));
  float e0 = __expf(s0-mx), e1 = __expf(s1-mx), e2 = __expf(s2-mx);
  float inv = __builtin_amdgcn_rcpf(e0+e1+e2);
  e0 *= inv; e1 *= inv; e2 *= inv;
  treprs[idx*3+0] = e0*xa[0] + e1*xa[3] + e2*xa[6];
  treprs[idx*3+1] = e0*xa[1] + e1*xa[4] + e2*xa[7];
  treprs[idx*3+2] = e0*xa[2] + e1*xa[5] + e2*xa[8];
}

// ---------- Kernel 2: weight-stationary encoder (unchanged) ----------------
__global__ __launch_bounds__(512, 2) void encoder_kernel(
    const bf16* __restrict__ encWF, const float* __restrict__ eWih,
    const float* __restrict__ ebih, const float* __restrict__ ebhh,
    const float* __restrict__ treprs, unsigned char* __restrict__ eo8,
    float* __restrict__ h_enc)
{
  __shared__ __align__(16) bf16  hbF[8*64*8];
  __shared__ __align__(16) bf16  hb_lin[4*264];
  __shared__ __align__(16) float hf[4*260];
  __shared__ __align__(16) f32x4 wihAll[768];
  __shared__ float bhhnL[256];
  __shared__ float xtL[2][16];

  const int tid = threadIdx.x;
  const int b0 = blockIdx.x * 4;

  for (int i = tid; i < 768; i += 512) {
    f32x4 w;
    w.x = eWih[i*3+0]; w.y = eWih[i*3+1]; w.z = eWih[i*3+2];
    w.w = (i < 512) ? (ebih[i] + ebhh[i]) : ebih[i];
    wihAll[i] = w;
    if (i >= 512) bhhnL[i-512] = ebhh[i];
  }
  for (int i = tid; i < 4*260; i += 512) hf[i] = 0.f;
  for (int i = tid; i < 8*64*8; i += 512) hbF[i] = __float2bfloat16(0.f);
  for (int i = tid; i < 4*264; i += 512) hb_lin[i] = __float2bfloat16(0.f);
  if (tid < 16) {
    int b = tid >> 2, f = tid & 3;
    xtL[0][tid] = (f < 3) ? treprs[((long)(b0+b)*T_LEN + 0)*3 + f] : 0.f;
  }

  const int lane = tid & 63;
  const int wv   = tid >> 6;
  const int nrow = lane & 15;
  const int quad = lane >> 4;

  s16x8 wf[32];
  #pragma unroll
  for (int u = 0; u < 4; ++u) {
    int tile = (u < 2) ? (2*wv + u) : (16 + 2*wv + (u-2));
    #pragma unroll
    for (int kc = 0; kc < 8; ++kc)
      wf[u*8+kc] = *(const s16x8*)(encWF + (((long)tile*8 + kc)*64 + lane)*8);
  }
  __syncthreads();

  for (int t = 0; t < 256; ++t) {
    s16x8 afr[8];
    #pragma unroll
    for (int kc = 0; kc < 8; ++kc)
      afr[kc] = *(const s16x8*)&hbF[(kc*64 + lane)*8];
    if (t >= 1 && tid < 128) {
      int b = tid >> 5, seg = tid & 31;
      s16x8 hv = *(const s16x8*)&hb_lin[b*264 + seg*8];
      *(uint2*)(eo8 + ((long)(b0+b)*T_LEN + (t-1))*H_DIM + seg*8) = pk8fp8(hv);
    }
    __syncthreads();

    f32x4 acc[6] = {};
    #pragma unroll
    for (int kc = 0; kc < 8; ++kc) {
      #pragma unroll
      for (int u = 0; u < 4; ++u)
        acc[u] = mfma16(afr[kc], wf[u*8+kc], acc[u]);
    }
    #pragma unroll
    for (int half = 0; half < 2; ++half) {
      s16x8 nf[8];
      #pragma unroll
      for (int kc = 0; kc < 8; ++kc)
        nf[kc] = *(const s16x8*)(encWF + (((long)(32 + 2*wv + half)*8 + kc)*64 + lane)*8);
      #pragma unroll
      for (int kc = 0; kc < 8; ++kc)
        acc[4+half] = mfma16(afr[kc], nf[kc], acc[4+half]);
    }

    if (t < 255 && tid < 16) {
      int b = tid >> 2, f = tid & 3;
      xtL[(t+1)&1][tid] = (f < 3) ? treprs[((long)(b0+b)*T_LEN + (t+1))*3 + f] : 0.f;
    }

    {
      float x0 = xtL[t & 1][quad*4+0];
      float x1 = xtL[t & 1][quad*4+1];
      float x2 = xtL[t & 1][quad*4+2];
      #pragma unroll
      for (int c = 0; c < 2; ++c) {
        int j = wv*32 + c*16 + nrow;
        f32x4 wr = wihAll[j];
        f32x4 wz = wihAll[256+j];
        f32x4 wn = wihAll[512+j];
        float rg = fsig(wr.x*x0 + wr.y*x1 + wr.z*x2 + wr.w + acc[c][0]);
        float zg = fsig(wz.x*x0 + wz.y*x1 + wz.z*x2 + wz.w + acc[2+c][0]);
        float ng = ftanh(wn.x*x0 + wn.y*x1 + wn.z*x2 + wn.w
                         + rg*(acc[4+c][0] + bhhnL[j]));
        float hold = hf[quad*260 + j];
        float hnew = ng + zg*(hold - ng);
        hf[quad*260 + j] = hnew;
        bf16 hv = __float2bfloat16(hnew);
        hb_lin[quad*264 + j] = hv;
        hbF[((j>>5)*64 + ((j>>3)&3)*16 + 4*quad)*8 + (j&7)] = hv;
      }
    }
    __syncthreads();
  }

  if (tid < 128) {
    int b = tid >> 5, seg = tid & 31;
    s16x8 hv = *(const s16x8*)&hb_lin[b*264 + seg*8];
    *(uint2*)(eo8 + ((long)(b0+b)*T_LEN + 255)*H_DIM + seg*8) = pk8fp8(hv);
  }
  for (int i = tid; i < 4*256; i += 512) {
    int m = i >> 8, j = i & 255;
    h_enc[(long)(b0+m)*H_DIM + j] = hf[m*260 + j];
  }
}

// ---------- Kernel 3: enc_proj GEMM (wtEncF pre-scaled x2 upstream) --------
__global__ __launch_bounds__(256) void proj_kernel(
    const unsigned char* __restrict__ eo8, const bf16* __restrict__ wtEncF,
    unsigned char* __restrict__ ep8)
{
  __shared__ __align__(16) bf16 Asm[4*8*64*8];
  __shared__ __align__(16) unsigned char Cst[64*256];
  const int tid = threadIdx.x;
  const long R0 = (long)blockIdx.x * 64;
  const int lane = tid & 63, wv = tid >> 6;
  const int nrow = lane & 15, quad = lane >> 4;

  #pragma unroll
  for (int s8 = 0; s8 < 8; ++s8) {
    int s = tid + s8*256;
    int l = s & 63, kc = (s>>6)&7, at = s>>9;
    int m = at*16 + (l&15), k = kc*32 + ((l>>4)&3)*8;
    uint2 v = *(const uint2*)(eo8 + (R0+m)*H_DIM + k);
    s16x8 o; f32x2 d;
    d = fp8pk2f<0>(v.x); o[0] = __bfloat16_as_short(__float2bfloat16(d.x)); o[1] = __bfloat16_as_short(__float2bfloat16(d.y));
    d = fp8pk2f<1>(v.x); o[2] = __bfloat16_as_short(__float2bfloat16(d.x)); o[3] = __bfloat16_as_short(__float2bfloat16(d.y));
    d = fp8pk2f<0>(v.y); o[4] = __bfloat16_as_short(__float2bfloat16(d.x)); o[5] = __bfloat16_as_short(__float2bfloat16(d.y));
    d = fp8pk2f<1>(v.y); o[6] = __bfloat16_as_short(__float2bfloat16(d.x)); o[7] = __bfloat16_as_short(__float2bfloat16(d.y));
    *(s16x8*)&Asm[s*8] = o;
  }
  __syncthreads();

  f32x4 acc[16];
  #pragma unroll
  for (int n = 0; n < 16; ++n) acc[n] = f32x4{0.f,0.f,0.f,0.f};
  #pragma unroll
  for (int kc = 0; kc < 8; ++kc) {
    s16x8 a = *(const s16x8*)&Asm[((wv*8 + kc)*64 + lane)*8];
    #pragma unroll
    for (int nt = 0; nt < 16; ++nt) {
      s16x8 b = *(const s16x8*)(wtEncF + ((nt*8 + kc)*64 + lane)*8);
      acc[nt] = mfma16(a, b, acc[nt]);
    }
  }
  #pragma unroll
  for (int nt = 0; nt < 16; ++nt)
    #pragma unroll
    for (int r = 0; r < 4; ++r)
      Cst[(wv*16 + quad*4 + r)*256 + nt*16 + nrow] = f2fp8(acc[nt][r]);
  __syncthreads();

  {
    int row = tid >> 2, seg = tid & 3;
    #pragma unroll
    for (int p = 0; p < 4; ++p)
      *(uint4*)(ep8 + (R0+row)*H_DIM + seg*64 + p*16) =
          *(const uint4*)&Cst[row*256 + seg*64 + p*16];
  }
}

// ---------- Kernel 4: decoder, 512 thr, B_wg=2, grid 512 -------------------
// r11 base + phase fusion: softmax folded into context phase (per-wave
// redundant normalization, scores live in twL), single-phase FC. 6 barriers
// per step instead of 8; no idle-wave phases.
// NOTE: 1024-thread variants of this body ALWAYS spill (r0/r4/r12).
__global__ __launch_bounds__(512, 4) void decoder_kernel(
    const float* __restrict__ x, const bf16* __restrict__ wtDec,
    const float* __restrict__ bt, const float* __restrict__ vt,
    const bf16* __restrict__ wihPD, const bf16* __restrict__ whhD,
    const float* __restrict__ dbih, const float* __restrict__ dbhh,
    const float* __restrict__ Wfc, const float* __restrict__ bfc,
    const unsigned char* __restrict__ eo8, const unsigned char* __restrict__ ep8,
    const float* __restrict__ h_enc, float* __restrict__ out)
{
  __shared__ __align__(16) float hfL[2*260];
  __shared__ __align__(16) bf16  hbL[16*264];   // rows 2..15 stay zero
  __shared__ __align__(16) float qP[2*276];     // chunk-major 2*q, stride 17
  __shared__ __align__(16) float vtP[276];      // chunk-major 2*vt, stride 17
  __shared__ float vtSumL;                      // sum(vt)
  __shared__ float twL[2*260];                  // raw scores (pre-softmax)
  __shared__ __align__(16) bf16  inpb[16*296];  // rows 2..15 stay zero
  __shared__ float btL[256];
  __shared__ float bsumL[512];
  __shared__ float bihnL[256];
  __shared__ float bhhnL[256];
  __shared__ float ghL[6*260];                  // r/z/n hidden-gate stash
  __shared__ __align__(16) float WfcL[9*260];
  __shared__ float bfcL[9];
  __shared__ float decin[24];
  __shared__ __align__(16) float scratch[4096];

  const int tid = threadIdx.x;
  const int b0 = blockIdx.x * 2;

  for (int i = tid; i < 256; i += 512) {
    vtP[(i>>4)*17 + (i&15)] = 2.f * vt[i];
    btL[i] = 2.f * bt[i];
    bihnL[i] = dbih[512+i]; bhhnL[i] = dbhh[512+i];
  }
  if (tid < 512) bsumL[tid] = dbih[tid] + dbhh[tid];
  for (int i = tid; i < 9*256; i += 512) { int o = i >> 8, k = i & 255; WfcL[o*260+k] = Wfc[i]; }
  if (tid < 9) bfcL[tid] = bfc[tid];
  for (int i = tid; i < 2*260; i += 512) { int m = i/260, j = i - m*260; hfL[i] = (j < 256) ? h_enc[(long)(b0+m)*H_DIM + j] : 0.f; }
  for (int i = tid; i < 16*264; i += 512) {
    int m = i/264, j = i - m*264;
    hbL[i] = (m < 2 && j < 256) ? __float2bfloat16(h_enc[(long)(b0+m)*H_DIM + j])
                                : __float2bfloat16(0.f);
  }
  for (int i = tid; i < 16*296; i += 512) inpb[i] = __float2bfloat16(0.f);
  if (tid < 18) { int b = tid/9, o = tid - b*9; decin[b*12+o] = x[((long)(b0+b)*T_LEN + (T_LEN-1))*9 + o]; }
  __syncthreads();

  // vtSum = sum(vt) = 0.5 * sum(vtP); first use is in phase 2, ordered by
  // phase-1's terminating barrier.
  if (tid == 0) {
    float s = 0.f;
    for (int c = 0; c < 16; ++c)
      #pragma unroll
      for (int e = 0; e < 16; ++e) s += vtP[c*17 + e];
    vtSumL = 0.5f * s;
  }

  const int lane = tid & 63;
  const int wv   = tid >> 6;          // 0..7
  const int nrow = lane & 15;
  const int quad = lane >> 4;
  const int jr0  = wv*16 + nrow;      // first gate/q column tile; second: +128

  for (int s = 0; s < PRED_LEN; ++s) {
    // ---- phase 1: q + gh MFMAs; 2 tiles SERIAL (4 accs live at a time) ----
    #pragma unroll 1
    for (int half = 0; half < 2; ++half) {
      const int j = jr0 + half*128;
      f32x4 qa = {}, ghr = {}, ghz = {}, ghn = {};
      #pragma unroll
      for (int kc = 0; kc < 8; ++kc) {
        s16x8 a = *(const s16x8*)&hbL[nrow*264 + kc*32 + quad*8];
        qa  = mfma16(a, *(const s16x8*)(wtDec + (long)j*256 + kc*32 + quad*8), qa);
        ghr = mfma16(a, *(const s16x8*)(whhD + (long)j*256 + kc*32 + quad*8), ghr);
        ghz = mfma16(a, *(const s16x8*)(whhD + (long)(256+j)*256 + kc*32 + quad*8), ghz);
        ghn = mfma16(a, *(const s16x8*)(whhD + (long)(512+j)*256 + kc*32 + quad*8), ghn);
      }
      if (quad == 0) {
        #pragma unroll
        for (int r = 0; r < 2; ++r) {
          qP[r*276 + (j>>4)*17 + (j&15)] = qa[r] + btL[j];
          ghL[(0+r)*260 + j]  = ghr[r];
          ghL[(2+r)*260 + j]  = ghz[r];
          ghL[(4+r)*260 + j]  = ghn[r];
        }
      }
    }
    __syncthreads();

    // ---- phase 2: scores -> twL, COALESCED + restructured tanh ----
    // wave: b = wv>>2, w4 = wv&3 covers t in [w4*64, w4*64+64)
    // lane: tr = lane>>4 (row in 4-row group), kc = lane&15 (16-B chunk)
    {
      int b = wv >> 2, w4 = wv & 3;
      int kc = lane & 15, tr = lane >> 4;
      const float* qp = &qP[b*276];
      const unsigned char* epb =
          ep8 + ((long)(b0+b)*T_LEN + w4*64)*H_DIM + kc*16;
      const int k = kc*17;
      const float vts = vtSumL;
      #pragma unroll 2
      for (int i = 0; i < 16; ++i) {
        int t4 = i*4 + tr;
        uint4 pv = *(const uint4*)(epb + (long)t4*H_DIM);
        float s0 = 0.f, s1 = 0.f;
        f32x2 d;
        d = fp8pk2f<0>(pv.x); s0 += vtP[k+0]*__builtin_amdgcn_rcpf(1.f+__expf(d.x+qp[k+0]));   s1 += vtP[k+1]*__builtin_amdgcn_rcpf(1.f+__expf(d.y+qp[k+1]));
        d = fp8pk2f<1>(pv.x); s0 += vtP[k+2]*__builtin_amdgcn_rcpf(1.f+__expf(d.x+qp[k+2]));   s1 += vtP[k+3]*__builtin_amdgcn_rcpf(1.f+__expf(d.y+qp[k+3]));
        d = fp8pk2f<0>(pv.y); s0 += vtP[k+4]*__builtin_amdgcn_rcpf(1.f+__expf(d.x+qp[k+4]));   s1 += vtP[k+5]*__builtin_amdgcn_rcpf(1.f+__expf(d.y+qp[k+5]));
        d = fp8pk2f<1>(pv.y); s0 += vtP[k+6]*__builtin_amdgcn_rcpf(1.f+__expf(d.x+qp[k+6]));   s1 += vtP[k+7]*__builtin_amdgcn_rcpf(1.f+__expf(d.y+qp[k+7]));
        d = fp8pk2f<0>(pv.z); s0 += vtP[k+8]*__builtin_amdgcn_rcpf(1.f+__expf(d.x+qp[k+8]));   s1 += vtP[k+9]*__builtin_amdgcn_rcpf(1.f+__expf(d.y+qp[k+9]));
        d = fp8pk2f<1>(pv.z); s0 += vtP[k+10]*__builtin_amdgcn_rcpf(1.f+__expf(d.x+qp[k+10])); s1 += vtP[k+11]*__builtin_amdgcn_rcpf(1.f+__expf(d.y+qp[k+11]));
        d = fp8pk2f<0>(pv.w); s0 += vtP[k+12]*__builtin_amdgcn_rcpf(1.f+__expf(d.x+qp[k+12])); s1 += vtP[k+13]*__builtin_amdgcn_rcpf(1.f+__expf(d.y+qp[k+13]));
        d = fp8pk2f<1>(pv.w); s0 += vtP[k+14]*__builtin_amdgcn_rcpf(1.f+__expf(d.x+qp[k+14])); s1 += vtP[k+15]*__builtin_amdgcn_rcpf(1.f+__expf(d.y+qp[k+15]));
        float sc = s0 + s1;
        #pragma unroll
        for (int off = 1; off < 16; off <<= 1) sc += __shfl_xor(sc, off);
        if (kc == 0) twL[b*260 + w4*64 + t4] = vts - sc;
      }
    }
    __syncthreads();

    // ---- phase 2bc: per-wave softmax (redundant) + context partials ----
    // wave tq handles t window [tq*32, tq*32+32); lane: b = lane>>5 batch,
    // hl = lane&31 (h-chunk of 8 / softmax slot).
    {
      int tq = wv;
      int b = lane >> 5, hl = lane & 31;
      // softmax normalization for batch b across this 32-lane half-wave
      float v8[8];
      float mx = -1e30f;
      #pragma unroll
      for (int u = 0; u < 8; ++u) {
        v8[u] = twL[b*260 + hl + 32*u];
        mx = fmaxf(mx, v8[u]);
      }
      #pragma unroll
      for (int off = 1; off < 32; off <<= 1) mx = fmaxf(mx, __shfl_xor(mx, off));
      float sum = 0.f;
      #pragma unroll
      for (int u = 0; u < 8; ++u) sum += __expf(v8[u] - mx);
      #pragma unroll
      for (int off = 1; off < 32; off <<= 1) sum += __shfl_xor(sum, off);
      float inv = __builtin_amdgcn_rcpf(sum);
      // this lane's softmax weight for t = tq*32 + hl (of batch b)
      float mytw = __expf(twL[b*260 + tq*32 + hl] - mx) * inv;

      int h8 = hl * 8;
      const unsigned char* eob = eo8 + ((long)(b0+b)*T_LEN + tq*32)*H_DIM + h8;
      float c[8] = {};
      #pragma unroll 8
      for (int t = 0; t < 32; ++t) {
        uint2 ev = *(const uint2*)(eob + (long)t*H_DIM);
        float w = __shfl(mytw, (b << 5) + t);
        f32x2 d0 = fp8pk2f<0>(ev.x);
        f32x2 d1 = fp8pk2f<1>(ev.x);
        f32x2 d2 = fp8pk2f<0>(ev.y);
        f32x2 d3 = fp8pk2f<1>(ev.y);
        c[0] += w*d0.x; c[1] += w*d0.y; c[2] += w*d1.x; c[3] += w*d1.y;
        c[4] += w*d2.x; c[5] += w*d2.y; c[6] += w*d3.x; c[7] += w*d3.y;
      }
      f32x4 cc0; cc0.x = c[0]; cc0.y = c[1]; cc0.z = c[2]; cc0.w = c[3];
      f32x4 cc1; cc1.x = c[4]; cc1.y = c[5]; cc1.z = c[6]; cc1.w = c[7];
      *(f32x4*)&scratch[tq*512 + b*256 + h8 + 0] = cc0;
      *(f32x4*)&scratch[tq*512 + b*256 + h8 + 4] = cc1;
    }
    __syncthreads();

    // ---- phase 2d: reduce -> inpb ----
    {
      int b = tid >> 8, h = tid & 255;
      float sum = 0.f;
      #pragma unroll
      for (int tq = 0; tq < 8; ++tq) sum += scratch[tq*512 + b*256 + h];
      inpb[b*296 + 9 + h] = __float2bfloat16(sum);
    }
    if (tid < 18) {
      int bb = tid/9, o = tid - bb*9;
      inpb[bb*296 + o] = __float2bfloat16(decin[bb*12 + o]);
    }
    __syncthreads();

    // ---- phase 3: gi MFMAs; 2 tiles SERIAL; gh from LDS ----
    #pragma unroll 1
    for (int half = 0; half < 2; ++half) {
      const int j = jr0 + half*128;
      f32x4 gir = {}, giz = {}, gin = {};
      #pragma unroll
      for (int kc = 0; kc < 9; ++kc) {
        s16x8 a = *(const s16x8*)&inpb[nrow*296 + kc*32 + quad*8];
        gir = mfma16(a, *(const s16x8*)(wihPD + (long)j*288 + kc*32 + quad*8), gir);
        giz = mfma16(a, *(const s16x8*)(wihPD + (long)(256+j)*288 + kc*32 + quad*8), giz);
        gin = mfma16(a, *(const s16x8*)(wihPD + (long)(512+j)*288 + kc*32 + quad*8), gin);
      }
      if (quad == 0) {
        #pragma unroll
        for (int r = 0; r < 2; ++r) {
          float rg = fsig(gir[r] + ghL[(0+r)*260 + j] + bsumL[j]);
          float zg = fsig(giz[r] + ghL[(2+r)*260 + j] + bsumL[256+j]);
          float ng = ftanh(gin[r] + bihnL[j] + rg*(ghL[(4+r)*260 + j] + bhhnL[j]));
          float hold = hfL[r*260 + j];
          float hnew = ng + zg*(hold - ng);
          hfL[r*260 + j] = hnew;
          hbL[r*264 + j] = __float2bfloat16(hnew);
        }
      }
    }
    __syncthreads();

    // ---- phase 4: pred = h_new @ Wfc^T + bfc (single phase, 2 waves) ----
    if (wv < 2) {
      const int b = wv;
      #pragma unroll 1
      for (int o = 0; o < 9; ++o) {
        float ps = 0.f;
        #pragma unroll
        for (int kk = 0; kk < 4; ++kk)
          ps += hfL[b*260 + lane + kk*64] * WfcL[o*260 + lane + kk*64];
        #pragma unroll
        for (int off = 1; off < 64; off <<= 1) ps += __shfl_xor(ps, off);
        if (lane == 0) {
          float v = ps + bfcL[o];
          out[((long)(b0+b)*PRED_LEN + s)*9 + o] = v;
          decin[b*12 + o] = v;
        }
      }
    }
    __syncthreads();
  }
}

extern "C" void kernel_launch(void* const* d_in, const int* in_sizes, int n_in,
                              void* d_out, int out_size, void* d_ws, size_t ws_size,
                              hipStream_t stream)
{
  const float* x    = (const float*)d_in[0];
  const float* Wa   = (const float*)d_in[1];
  const float* ba   = (const float*)d_in[2];
  const float* va   = (const float*)d_in[3];
  const float* eWih = (const float*)d_in[4];
  const float* eWhh = (const float*)d_in[5];
  const float* ebih = (const float*)d_in[6];
  const float* ebhh = (const float*)d_in[7];
  const float* dWih = (const float*)d_in[8];
  const float* dWhh = (const float*)d_in[9];
  const float* dbih = (const float*)d_in[10];
  const float* dbhh = (const float*)d_in[11];
  const float* Wt   = (const float*)d_in[12];
  const float* bt   = (const float*)d_in[13];
  const float* vt   = (const float*)d_in[14];
  const float* Wfc  = (const float*)d_in[15];
  const float* bfc  = (const float*)d_in[16];
  float* out = (float*)d_out;

  char* ws = (char*)d_ws;
  size_t off = 0;
  bf16* encWF   = (bf16*)(ws + off); off += (size_t)48*8*64*8*sizeof(bf16);
  bf16* wtEncF  = (bf16*)(ws + off); off += (size_t)16*8*64*8*sizeof(bf16);
  bf16* wtDec   = (bf16*)(ws + off); off += (size_t)256*256*sizeof(bf16);
  bf16* whhD    = (bf16*)(ws + off); off += (size_t)768*256*sizeof(bf16);
  bf16* wihPD   = (bf16*)(ws + off); off += (size_t)768*288*sizeof(bf16);
  float* treprs = (float*)(ws + off); off += (size_t)B_TOT*T_LEN*3*sizeof(float);
  float* h_enc  = (float*)(ws + off); off += (size_t)B_TOT*H_DIM*sizeof(float);
  unsigned char* eo8 = (unsigned char*)(ws + off); off += (size_t)B_TOT*T_LEN*H_DIM;
  unsigned char* ep8 = (unsigned char*)(ws + off); off += (size_t)B_TOT*T_LEN*H_DIM;

  if (ws_size < off) return;

  convert_kernel<<<(768*288 + 255)/256, 256, 0, stream>>>(
      eWhh, Wt, dWhh, dWih, encWF, wtEncF, wtDec, whhD, wihPD);
  agent_attn_kernel<<<B_TOT*T_LEN/256, 256, 0, stream>>>(x, Wa, ba, va, treprs);
  encoder_kernel<<<B_TOT/4, 512, 0, stream>>>(encWF, eWih, ebih, ebhh,
                                              treprs, eo8, h_enc);
  proj_kernel<<<B_TOT*T_LEN/64, 256, 0, stream>>>(eo8, wtEncF, ep8);
  decoder_kernel<<<B_TOT/2, 512, 0, stream>>>(x, wtDec, bt, vt, wihPD, whhD,
                                              dbih, dbhh, Wfc, bfc, eo8, ep8,
                                              h_enc, out);
}

// Round 16
// 1569.193 us; speedup vs baseline: 1.0306x; 1.0306x over previous
//
#include <hip/hip_runtime.h>
#include <hip/hip_bf16.h>

typedef __hip_bfloat16 bf16;
typedef __attribute__((ext_vector_type(8))) short s16x8;
typedef __attribute__((ext_vector_type(4))) float f32x4;
typedef __attribute__((ext_vector_type(2))) float f32x2;

#define B_TOT 1024
#define T_LEN 256
#define H_DIM 256
#define PRED_LEN 16

__device__ __forceinline__ float b2f(short u) {
  union { unsigned int i; float f; } c;
  c.i = ((unsigned int)(unsigned short)u) << 16;
  return c.f;
}
__device__ __forceinline__ float fsig(float x) {
  return __builtin_amdgcn_rcpf(1.f + __expf(-x));
}
__device__ __forceinline__ float ftanh(float x) {
  return 1.f - 2.f * __builtin_amdgcn_rcpf(1.f + __expf(2.f * x));
}
__device__ __forceinline__ f32x4 mfma16(s16x8 a, s16x8 b, f32x4 c) {
  return __builtin_amdgcn_mfma_f32_16x16x32_bf16(a, b, c, 0, 0, 0);
}
template <int HI>
__device__ __forceinline__ f32x2 fp8pk2f(unsigned int pk) {
  return __builtin_amdgcn_cvt_pk_f32_fp8(pk, HI);
}
__device__ __forceinline__ unsigned char f2fp8(float v) {
  return (unsigned char)(__builtin_amdgcn_cvt_pk_fp8_f32(v, v, 0, 0) & 0xff);
}
__device__ __forceinline__ uint2 pk8fp8(s16x8 hv) {
  unsigned int lo = 0, hi = 0;
  lo = __builtin_amdgcn_cvt_pk_fp8_f32(b2f(hv[0]), b2f(hv[1]), lo, 0);
  lo = __builtin_amdgcn_cvt_pk_fp8_f32(b2f(hv[2]), b2f(hv[3]), lo, 1);
  hi = __builtin_amdgcn_cvt_pk_fp8_f32(b2f(hv[4]), b2f(hv[5]), hi, 0);
  hi = __builtin_amdgcn_cvt_pk_fp8_f32(b2f(hv[6]), b2f(hv[7]), hi, 1);
  uint2 w; w.x = lo; w.y = hi; return w;
}

// ---------- Kernel 0: pack fp32 weights -> bf16 ws layouts ------------------
// wtEncF and wtDec PRE-SCALED by 2 (ep8 = 2*enc_proj, q = 2*q_orig) for the
// restructured tanh in decoder phase 2.
__global__ __launch_bounds__(256) void convert_kernel(
    const float* __restrict__ eWhh, const float* __restrict__ Wt,
    const float* __restrict__ dWhh, const float* __restrict__ dWih,
    bf16* __restrict__ encWF, bf16* __restrict__ wtEncF,
    bf16* __restrict__ wtDec, bf16* __restrict__ whhD, bf16* __restrict__ wihPD)
{
  int i = blockIdx.x*256 + threadIdx.x;
  if (i < 24576) {           // encWF fragment slots
    int l = i & 63, kc = (i>>6)&7, tile = i>>9;
    int j = tile*16 + (l&15);
    int k = kc*32 + ((l>>4)&3)*8;
    #pragma unroll
    for (int e = 0; e < 8; ++e)
      encWF[i*8+e] = __float2bfloat16(eWhh[j*256 + k + e]);
  } else if (i < 32768) {    // wtEncF fragment slots (x2 scale)
    int s = i - 24576;
    int l = s & 63, kc = (s>>6)&7, tile = s>>9;
    int j = tile*16 + (l&15);
    int k = kc*32 + ((l>>4)&3)*8;
    #pragma unroll
    for (int e = 0; e < 8; ++e)
      wtEncF[s*8+e] = __float2bfloat16(2.f * Wt[j*512 + 256 + k + e]);
  }
  if (i < 768*288) {
    int g = i / 288, k = i - g*288;
    wihPD[i] = __float2bfloat16((k < 265) ? dWih[g*265 + k] : 0.f);
  }
  if (i < 256*256) {         // wtDec (x2 scale)
    int g = i >> 8, k = i & 255;
    wtDec[i] = __float2bfloat16(2.f * Wt[g*512 + k]);
  }
  if (i < 768*256) whhD[i] = __float2bfloat16(dWhh[i]);
}

// ---------- Kernel 1: agent attention (tanh restructured) ------------------
__global__ __launch_bounds__(256) void agent_attn_kernel(
    const float* __restrict__ x, const float* __restrict__ Wa,
    const float* __restrict__ ba, const float* __restrict__ va,
    float* __restrict__ treprs)
{
  __shared__ float w0[256], w1[256], w2[256], baL[256], vaL[256];
  __shared__ float halfVsum;
  int tid = threadIdx.x;
  w0[tid] = 2.f * Wa[tid*3+0];
  w1[tid] = 2.f * Wa[tid*3+1];
  w2[tid] = 2.f * Wa[tid*3+2];
  baL[tid] = 2.f * ba[tid];
  vaL[tid] = 2.f * va[tid];
  __syncthreads();
  if (tid == 0) {
    float s = 0.f;
    for (int i = 0; i < 256; ++i) s += vaL[i];
    halfVsum = 0.25f * s;      // = 0.5 * sum(va) ... vaL = 2*va
  }
  __syncthreads();
  long idx = (long)blockIdx.x * 256 + tid;
  float xa[9];
  #pragma unroll
  for (int i = 0; i < 9; ++i) xa[i] = x[idx*9 + i];
  float s0 = 0.f, s1 = 0.f, s2 = 0.f;
  for (int h = 0; h < 256; ++h) {
    float a0 = w0[h], a1 = w1[h], a2 = w2[h], bb = baL[h], vv = vaL[h];
    s0 += vv * __builtin_amdgcn_rcpf(1.f + __expf(a0*xa[0] + a1*xa[1] + a2*xa[2] + bb));
    s1 += vv * __builtin_amdgcn_rcpf(1.f + __expf(a0*xa[3] + a1*xa[4] + a2*xa[5] + bb));
    s2 += vv * __builtin_amdgcn_rcpf(1.f + __expf(a0*xa[6] + a1*xa[7] + a2*xa[8] + bb));
  }
  float vs = 2.f * halfVsum;
  s0 = vs - s0; s1 = vs - s1; s2 = vs - s2;
  float mx = fmaxf(s0, fmaxf(s1, s2));
  float e0 = __expf(s0-mx), e1 = __expf(s1-mx), e2 = __expf(s2-mx);
  float inv = __builtin_amdgcn_rcpf(e0+e1+e2);
  e0 *= inv; e1 *= inv; e2 *= inv;
  treprs[idx*3+0] = e0*xa[0] + e1*xa[3] + e2*xa[6];
  treprs[idx*3+1] = e0*xa[1] + e1*xa[4] + e2*xa[7];
  treprs[idx*3+2] = e0*xa[2] + e1*xa[5] + e2*xa[8];
}

// ---------- Kernel 2: weight-stationary encoder (unchanged) ----------------
__global__ __launch_bounds__(512, 2) void encoder_kernel(
    const bf16* __restrict__ encWF, const float* __restrict__ eWih,
    const float* __restrict__ ebih, const float* __restrict__ ebhh,
    const float* __restrict__ treprs, unsigned char* __restrict__ eo8,
    float* __restrict__ h_enc)
{
  __shared__ __align__(16) bf16  hbF[8*64*8];
  __shared__ __align__(16) bf16  hb_lin[4*264];
  __shared__ __align__(16) float hf[4*260];
  __shared__ __align__(16) f32x4 wihAll[768];
  __shared__ float bhhnL[256];
  __shared__ float xtL[2][16];

  const int tid = threadIdx.x;
  const int b0 = blockIdx.x * 4;

  for (int i = tid; i < 768; i += 512) {
    f32x4 w;
    w.x = eWih[i*3+0]; w.y = eWih[i*3+1]; w.z = eWih[i*3+2];
    w.w = (i < 512) ? (ebih[i] + ebhh[i]) : ebih[i];
    wihAll[i] = w;
    if (i >= 512) bhhnL[i-512] = ebhh[i];
  }
  for (int i = tid; i < 4*260; i += 512) hf[i] = 0.f;
  for (int i = tid; i < 8*64*8; i += 512) hbF[i] = __float2bfloat16(0.f);
  for (int i = tid; i < 4*264; i += 512) hb_lin[i] = __float2bfloat16(0.f);
  if (tid < 16) {
    int b = tid >> 2, f = tid & 3;
    xtL[0][tid] = (f < 3) ? treprs[((long)(b0+b)*T_LEN + 0)*3 + f] : 0.f;
  }

  const int lane = tid & 63;
  const int wv   = tid >> 6;
  const int nrow = lane & 15;
  const int quad = lane >> 4;

  s16x8 wf[32];
  #pragma unroll
  for (int u = 0; u < 4; ++u) {
    int tile = (u < 2) ? (2*wv + u) : (16 + 2*wv + (u-2));
    #pragma unroll
    for (int kc = 0; kc < 8; ++kc)
      wf[u*8+kc] = *(const s16x8*)(encWF + (((long)tile*8 + kc)*64 + lane)*8);
  }
  __syncthreads();

  for (int t = 0; t < 256; ++t) {
    s16x8 afr[8];
    #pragma unroll
    for (int kc = 0; kc < 8; ++kc)
      afr[kc] = *(const s16x8*)&hbF[(kc*64 + lane)*8];
    if (t >= 1 && tid < 128) {
      int b = tid >> 5, seg = tid & 31;
      s16x8 hv = *(const s16x8*)&hb_lin[b*264 + seg*8];
      *(uint2*)(eo8 + ((long)(b0+b)*T_LEN + (t-1))*H_DIM + seg*8) = pk8fp8(hv);
    }
    __syncthreads();

    f32x4 acc[6] = {};
    #pragma unroll
    for (int kc = 0; kc < 8; ++kc) {
      #pragma unroll
      for (int u = 0; u < 4; ++u)
        acc[u] = mfma16(afr[kc], wf[u*8+kc], acc[u]);
    }
    #pragma unroll
    for (int half = 0; half < 2; ++half) {
      s16x8 nf[8];
      #pragma unroll
      for (int kc = 0; kc < 8; ++kc)
        nf[kc] = *(const s16x8*)(encWF + (((long)(32 + 2*wv + half)*8 + kc)*64 + lane)*8);
      #pragma unroll
      for (int kc = 0; kc < 8; ++kc)
        acc[4+half] = mfma16(afr[kc], nf[kc], acc[4+half]);
    }

    if (t < 255 && tid < 16) {
      int b = tid >> 2, f = tid & 3;
      xtL[(t+1)&1][tid] = (f < 3) ? treprs[((long)(b0+b)*T_LEN + (t+1))*3 + f] : 0.f;
    }

    {
      float x0 = xtL[t & 1][quad*4+0];
      float x1 = xtL[t & 1][quad*4+1];
      float x2 = xtL[t & 1][quad*4+2];
      #pragma unroll
      for (int c = 0; c < 2; ++c) {
        int j = wv*32 + c*16 + nrow;
        f32x4 wr = wihAll[j];
        f32x4 wz = wihAll[256+j];
        f32x4 wn = wihAll[512+j];
        float rg = fsig(wr.x*x0 + wr.y*x1 + wr.z*x2 + wr.w + acc[c][0]);
        float zg = fsig(wz.x*x0 + wz.y*x1 + wz.z*x2 + wz.w + acc[2+c][0]);
        float ng = ftanh(wn.x*x0 + wn.y*x1 + wn.z*x2 + wn.w
                         + rg*(acc[4+c][0] + bhhnL[j]));
        float hold = hf[quad*260 + j];
        float hnew = ng + zg*(hold - ng);
        hf[quad*260 + j] = hnew;
        bf16 hv = __float2bfloat16(hnew);
        hb_lin[quad*264 + j] = hv;
        hbF[((j>>5)*64 + ((j>>3)&3)*16 + 4*quad)*8 + (j&7)] = hv;
      }
    }
    __syncthreads();
  }

  if (tid < 128) {
    int b = tid >> 5, seg = tid & 31;
    s16x8 hv = *(const s16x8*)&hb_lin[b*264 + seg*8];
    *(uint2*)(eo8 + ((long)(b0+b)*T_LEN + 255)*H_DIM + seg*8) = pk8fp8(hv);
  }
  for (int i = tid; i < 4*256; i += 512) {
    int m = i >> 8, j = i & 255;
    h_enc[(long)(b0+m)*H_DIM + j] = hf[m*260 + j];
  }
}

// ---------- Kernel 3: enc_proj GEMM (wtEncF pre-scaled x2 upstream) --------
__global__ __launch_bounds__(256) void proj_kernel(
    const unsigned char* __restrict__ eo8, const bf16* __restrict__ wtEncF,
    unsigned char* __restrict__ ep8)
{
  __shared__ __align__(16) bf16 Asm[4*8*64*8];
  __shared__ __align__(16) unsigned char Cst[64*256];
  const int tid = threadIdx.x;
  const long R0 = (long)blockIdx.x * 64;
  const int lane = tid & 63, wv = tid >> 6;
  const int nrow = lane & 15, quad = lane >> 4;

  #pragma unroll
  for (int s8 = 0; s8 < 8; ++s8) {
    int s = tid + s8*256;
    int l = s & 63, kc = (s>>6)&7, at = s>>9;
    int m = at*16 + (l&15), k = kc*32 + ((l>>4)&3)*8;
    uint2 v = *(const uint2*)(eo8 + (R0+m)*H_DIM + k);
    s16x8 o; f32x2 d;
    d = fp8pk2f<0>(v.x); o[0] = __bfloat16_as_short(__float2bfloat16(d.x)); o[1] = __bfloat16_as_short(__float2bfloat16(d.y));
    d = fp8pk2f<1>(v.x); o[2] = __bfloat16_as_short(__float2bfloat16(d.x)); o[3] = __bfloat16_as_short(__float2bfloat16(d.y));
    d = fp8pk2f<0>(v.y); o[4] = __bfloat16_as_short(__float2bfloat16(d.x)); o[5] = __bfloat16_as_short(__float2bfloat16(d.y));
    d = fp8pk2f<1>(v.y); o[6] = __bfloat16_as_short(__float2bfloat16(d.x)); o[7] = __bfloat16_as_short(__float2bfloat16(d.y));
    *(s16x8*)&Asm[s*8] = o;
  }
  __syncthreads();

  f32x4 acc[16];
  #pragma unroll
  for (int n = 0; n < 16; ++n) acc[n] = f32x4{0.f,0.f,0.f,0.f};
  #pragma unroll
  for (int kc = 0; kc < 8; ++kc) {
    s16x8 a = *(const s16x8*)&Asm[((wv*8 + kc)*64 + lane)*8];
    #pragma unroll
    for (int nt = 0; nt < 16; ++nt) {
      s16x8 b = *(const s16x8*)(wtEncF + ((nt*8 + kc)*64 + lane)*8);
      acc[nt] = mfma16(a, b, acc[nt]);
    }
  }
  #pragma unroll
  for (int nt = 0; nt < 16; ++nt)
    #pragma unroll
    for (int r = 0; r < 4; ++r)
      Cst[(wv*16 + quad*4 + r)*256 + nt*16 + nrow] = f2fp8(acc[nt][r]);
  __syncthreads();

  {
    int row = tid >> 2, seg = tid & 3;
    #pragma unroll
    for (int p = 0; p < 4; ++p)
      *(uint4*)(ep8 + (R0+row)*H_DIM + seg*64 + p*16) =
          *(const uint4*)&Cst[row*256 + seg*64 + p*16];
  }
}

// ---------- Kernel 4: decoder, 512 thr, B_wg=2, grid 512 (r11 FINAL) -------
// Best verified configuration (1573.6 us total, decoder 975 us; reproduced
// r13 at 1575.2). 2 x 8-wave blocks per CU, spill-free at VGPR=64.
// Serialized dual-tile MFMA phases; coalesced phase 2 with restructured tanh
// (ep8/q pre-scaled x2; score = sum(vt) - sum(2vt*rcp(1+exp(2y)))).
// CLOSED routes (do not retry): 1024-thr blocks (always spill: r0/r4/r12),
// 32-wave occupancy, hoisted q/v register arrays (spill: r1/r3), MLP unroll
// (null: r9), phase fusion (regressed +71us: r15).
__global__ __launch_bounds__(512, 4) void decoder_kernel(
    const float* __restrict__ x, const bf16* __restrict__ wtDec,
    const float* __restrict__ bt, const float* __restrict__ vt,
    const bf16* __restrict__ wihPD, const bf16* __restrict__ whhD,
    const float* __restrict__ dbih, const float* __restrict__ dbhh,
    const float* __restrict__ Wfc, const float* __restrict__ bfc,
    const unsigned char* __restrict__ eo8, const unsigned char* __restrict__ ep8,
    const float* __restrict__ h_enc, float* __restrict__ out)
{
  __shared__ __align__(16) float hfL[2*260];
  __shared__ __align__(16) bf16  hbL[16*264];   // rows 2..15 stay zero
  __shared__ __align__(16) float qP[2*276];     // chunk-major 2*q, stride 17
  __shared__ __align__(16) float vtP[276];      // chunk-major 2*vt, stride 17
  __shared__ float vtSumL;                      // sum(vt)
  __shared__ float twL[2*260];
  __shared__ __align__(16) bf16  inpb[16*296];  // rows 2..15 stay zero
  __shared__ float btL[256];
  __shared__ float bsumL[512];
  __shared__ float bihnL[256];
  __shared__ float bhhnL[256];
  __shared__ float ghL[6*260];                  // r/z/n hidden-gate stash
  __shared__ __align__(16) float WfcL[9*260];
  __shared__ float bfcL[9];
  __shared__ float decin[24];
  __shared__ __align__(16) float scratch[4096];

  const int tid = threadIdx.x;
  const int b0 = blockIdx.x * 2;

  for (int i = tid; i < 256; i += 512) {
    vtP[(i>>4)*17 + (i&15)] = 2.f * vt[i];
    btL[i] = 2.f * bt[i];
    bihnL[i] = dbih[512+i]; bhhnL[i] = dbhh[512+i];
  }
  if (tid < 512) bsumL[tid] = dbih[tid] + dbhh[tid];
  for (int i = tid; i < 9*256; i += 512) { int o = i >> 8, k = i & 255; WfcL[o*260+k] = Wfc[i]; }
  if (tid < 9) bfcL[tid] = bfc[tid];
  for (int i = tid; i < 2*260; i += 512) { int m = i/260, j = i - m*260; hfL[i] = (j < 256) ? h_enc[(long)(b0+m)*H_DIM + j] : 0.f; }
  for (int i = tid; i < 16*264; i += 512) {
    int m = i/264, j = i - m*264;
    hbL[i] = (m < 2 && j < 256) ? __float2bfloat16(h_enc[(long)(b0+m)*H_DIM + j])
                                : __float2bfloat16(0.f);
  }
  for (int i = tid; i < 16*296; i += 512) inpb[i] = __float2bfloat16(0.f);
  if (tid < 18) { int b = tid/9, o = tid - b*9; decin[b*12+o] = x[((long)(b0+b)*T_LEN + (T_LEN-1))*9 + o]; }
  __syncthreads();

  // vtSum = sum(vt) = 0.5 * sum(vtP); first use is in phase 2, ordered by
  // phase-1's terminating barrier.
  if (tid == 0) {
    float s = 0.f;
    for (int c = 0; c < 16; ++c)
      #pragma unroll
      for (int e = 0; e < 16; ++e) s += vtP[c*17 + e];
    vtSumL = 0.5f * s;
  }

  const int lane = tid & 63;
  const int wv   = tid >> 6;          // 0..7
  const int nrow = lane & 15;
  const int quad = lane >> 4;
  const int jr0  = wv*16 + nrow;      // first gate/q column tile; second: +128

  for (int s = 0; s < PRED_LEN; ++s) {
    // ---- phase 1: q + gh MFMAs; 2 tiles SERIAL (4 accs live at a time) ----
    #pragma unroll 1
    for (int half = 0; half < 2; ++half) {
      const int j = jr0 + half*128;
      f32x4 qa = {}, ghr = {}, ghz = {}, ghn = {};
      #pragma unroll
      for (int kc = 0; kc < 8; ++kc) {
        s16x8 a = *(const s16x8*)&hbL[nrow*264 + kc*32 + quad*8];
        qa  = mfma16(a, *(const s16x8*)(wtDec + (long)j*256 + kc*32 + quad*8), qa);
        ghr = mfma16(a, *(const s16x8*)(whhD + (long)j*256 + kc*32 + quad*8), ghr);
        ghz = mfma16(a, *(const s16x8*)(whhD + (long)(256+j)*256 + kc*32 + quad*8), ghz);
        ghn = mfma16(a, *(const s16x8*)(whhD + (long)(512+j)*256 + kc*32 + quad*8), ghn);
      }
      if (quad == 0) {
        #pragma unroll
        for (int r = 0; r < 2; ++r) {
          qP[r*276 + (j>>4)*17 + (j&15)] = qa[r] + btL[j];
          ghL[(0+r)*260 + j]  = ghr[r];
          ghL[(2+r)*260 + j]  = ghz[r];
          ghL[(4+r)*260 + j]  = ghn[r];
        }
      }
    }
    __syncthreads();

    // ---- phase 2: scores, COALESCED + restructured tanh ----
    // wave: b = wv>>2, w4 = wv&3 covers t in [w4*64, w4*64+64)
    // lane: tr = lane>>4 (row in 4-row group), kc = lane&15 (16-B chunk)
    {
      int b = wv >> 2, w4 = wv & 3;
      int kc = lane & 15, tr = lane >> 4;
      const float* qp = &qP[b*276];
      const unsigned char* epb =
          ep8 + ((long)(b0+b)*T_LEN + w4*64)*H_DIM + kc*16;
      const int k = kc*17;
      const float vts = vtSumL;
      #pragma unroll 2
      for (int i = 0; i < 16; ++i) {
        int t4 = i*4 + tr;
        uint4 pv = *(const uint4*)(epb + (long)t4*H_DIM);
        float s0 = 0.f, s1 = 0.f;
        f32x2 d;
        d = fp8pk2f<0>(pv.x); s0 += vtP[k+0]*__builtin_amdgcn_rcpf(1.f+__expf(d.x+qp[k+0]));   s1 += vtP[k+1]*__builtin_amdgcn_rcpf(1.f+__expf(d.y+qp[k+1]));
        d = fp8pk2f<1>(pv.x); s0 += vtP[k+2]*__builtin_amdgcn_rcpf(1.f+__expf(d.x+qp[k+2]));   s1 += vtP[k+3]*__builtin_amdgcn_rcpf(1.f+__expf(d.y+qp[k+3]));
        d = fp8pk2f<0>(pv.y); s0 += vtP[k+4]*__builtin_amdgcn_rcpf(1.f+__expf(d.x+qp[k+4]));   s1 += vtP[k+5]*__builtin_amdgcn_rcpf(1.f+__expf(d.y+qp[k+5]));
        d = fp8pk2f<1>(pv.y); s0 += vtP[k+6]*__builtin_amdgcn_rcpf(1.f+__expf(d.x+qp[k+6]));   s1 += vtP[k+7]*__builtin_amdgcn_rcpf(1.f+__expf(d.y+qp[k+7]));
        d = fp8pk2f<0>(pv.z); s0 += vtP[k+8]*__builtin_amdgcn_rcpf(1.f+__expf(d.x+qp[k+8]));   s1 += vtP[k+9]*__builtin_amdgcn_rcpf(1.f+__expf(d.y+qp[k+9]));
        d = fp8pk2f<1>(pv.z); s0 += vtP[k+10]*__builtin_amdgcn_rcpf(1.f+__expf(d.x+qp[k+10])); s1 += vtP[k+11]*__builtin_amdgcn_rcpf(1.f+__expf(d.y+qp[k+11]));
        d = fp8pk2f<0>(pv.w); s0 += vtP[k+12]*__builtin_amdgcn_rcpf(1.f+__expf(d.x+qp[k+12])); s1 += vtP[k+13]*__builtin_amdgcn_rcpf(1.f+__expf(d.y+qp[k+13]));
        d = fp8pk2f<1>(pv.w); s0 += vtP[k+14]*__builtin_amdgcn_rcpf(1.f+__expf(d.x+qp[k+14])); s1 += vtP[k+15]*__builtin_amdgcn_rcpf(1.f+__expf(d.y+qp[k+15]));
        float sc = s0 + s1;
        #pragma unroll
        for (int off = 1; off < 16; off <<= 1) sc += __shfl_xor(sc, off);
        if (kc == 0) scratch[b*256 + w4*64 + t4] = vts - sc;
      }
    }
    __syncthreads();

    // ---- phase 2b: softmax (wave b handles batch row b) ----
    if (wv < 2) {
      float v4[4];
      float mx = -1e30f;
      #pragma unroll
      for (int i = 0; i < 4; ++i) { v4[i] = scratch[wv*256 + lane + 64*i]; mx = fmaxf(mx, v4[i]); }
      #pragma unroll
      for (int off = 1; off < 64; off <<= 1) mx = fmaxf(mx, __shfl_xor(mx, off));
      float sum = 0.f;
      #pragma unroll
      for (int i = 0; i < 4; ++i) { v4[i] = __expf(v4[i] - mx); sum += v4[i]; }
      #pragma unroll
      for (int off = 1; off < 64; off <<= 1) sum += __shfl_xor(sum, off);
      float inv = __builtin_amdgcn_rcpf(sum);
      #pragma unroll
      for (int i = 0; i < 4; ++i) twL[wv*260 + lane + 64*i] = v4[i] * inv;
    }
    __syncthreads();

    // ---- phase 2c: context partials (wave = tq of 8; unroll 8 MLP) ----
    {
      int tq = wv;                       // 0..7, t range tq*32..+32
      int b = lane >> 5, h8 = (lane & 31) * 8;
      const unsigned char* eob = eo8 + ((long)(b0+b)*T_LEN + tq*32)*H_DIM + h8;
      const float* tw = &twL[b*260 + tq*32];
      float c[8] = {};
      #pragma unroll 8
      for (int t = 0; t < 32; ++t) {
        uint2 ev = *(const uint2*)(eob + (long)t*H_DIM);
        float w = tw[t];
        f32x2 d0 = fp8pk2f<0>(ev.x);
        f32x2 d1 = fp8pk2f<1>(ev.x);
        f32x2 d2 = fp8pk2f<0>(ev.y);
        f32x2 d3 = fp8pk2f<1>(ev.y);
        c[0] += w*d0.x; c[1] += w*d0.y; c[2] += w*d1.x; c[3] += w*d1.y;
        c[4] += w*d2.x; c[5] += w*d2.y; c[6] += w*d3.x; c[7] += w*d3.y;
      }
      f32x4 cc0; cc0.x = c[0]; cc0.y = c[1]; cc0.z = c[2]; cc0.w = c[3];
      f32x4 cc1; cc1.x = c[4]; cc1.y = c[5]; cc1.z = c[6]; cc1.w = c[7];
      *(f32x4*)&scratch[tq*512 + b*256 + h8 + 0] = cc0;
      *(f32x4*)&scratch[tq*512 + b*256 + h8 + 4] = cc1;
    }
    __syncthreads();

    // ---- phase 2d: reduce -> inpb ----
    {
      int b = tid >> 8, h = tid & 255;
      float sum = 0.f;
      #pragma unroll
      for (int tq = 0; tq < 8; ++tq) sum += scratch[tq*512 + b*256 + h];
      inpb[b*296 + 9 + h] = __float2bfloat16(sum);
    }
    if (tid < 18) {
      int bb = tid/9, o = tid - bb*9;
      inpb[bb*296 + o] = __float2bfloat16(decin[bb*12 + o]);
    }
    __syncthreads();

    // ---- phase 3: gi MFMAs; 2 tiles SERIAL; gh from LDS ----
    #pragma unroll 1
    for (int half = 0; half < 2; ++half) {
      const int j = jr0 + half*128;
      f32x4 gir = {}, giz = {}, gin = {};
      #pragma unroll
      for (int kc = 0; kc < 9; ++kc) {
        s16x8 a = *(const s16x8*)&inpb[nrow*296 + kc*32 + quad*8];
        gir = mfma16(a, *(const s16x8*)(wihPD + (long)j*288 + kc*32 + quad*8), gir);
        giz = mfma16(a, *(const s16x8*)(wihPD + (long)(256+j)*288 + kc*32 + quad*8), giz);
        gin = mfma16(a, *(const s16x8*)(wihPD + (long)(512+j)*288 + kc*32 + quad*8), gin);
      }
      if (quad == 0) {
        #pragma unroll
        for (int r = 0; r < 2; ++r) {
          float rg = fsig(gir[r] + ghL[(0+r)*260 + j] + bsumL[j]);
          float zg = fsig(giz[r] + ghL[(2+r)*260 + j] + bsumL[256+j]);
          float ng = ftanh(gin[r] + bihnL[j] + rg*(ghL[(4+r)*260 + j] + bhhnL[j]));
          float hold = hfL[r*260 + j];
          float hnew = ng + zg*(hold - ng);
          hfL[r*260 + j] = hnew;
          hbL[r*264 + j] = __float2bfloat16(hnew);
        }
      }
    }
    __syncthreads();

    // ---- phase 4: pred = h_new @ Wfc^T + bfc ----
    if (tid < 144) {
      int b = tid / 72, rem = tid - b*72;
      int o = rem >> 3, ch = rem & 7;
      float ps = 0.f;
      #pragma unroll
      for (int k = ch*32; k < ch*32 + 32; ++k)
        ps += hfL[b*260 + k] * WfcL[o*260 + k];
      scratch[tid] = ps;
    }
    __syncthreads();
    if (tid < 18) {
      int b = tid / 9, o = tid - b*9;
      float sum = bfcL[o];
      #pragma unroll
      for (int ch = 0; ch < 8; ++ch) sum += scratch[b*72 + o*8 + ch];
      out[((long)(b0+b)*PRED_LEN + s)*9 + o] = sum;
      decin[b*12 + o] = sum;
    }
    __syncthreads();
  }
}

extern "C" void kernel_launch(void* const* d_in, const int* in_sizes, int n_in,
                              void* d_out, int out_size, void* d_ws, size_t ws_size,
                              hipStream_t stream)
{
  const float* x    = (const float*)d_in[0];
  const float* Wa   = (const float*)d_in[1];
  const float* ba   = (const float*)d_in[2];
  const float* va   = (const float*)d_in[3];
  const float* eWih = (const float*)d_in[4];
  const float* eWhh = (const float*)d_in[5];
  const float* ebih = (const float*)d_in[6];
  const float* ebhh = (const float*)d_in[7];
  const float* dWih = (const float*)d_in[8];
  const float* dWhh = (const float*)d_in[9];
  const float* dbih = (const float*)d_in[10];
  const float* dbhh = (const float*)d_in[11];
  const float* Wt   = (const float*)d_in[12];
  const float* bt   = (const float*)d_in[13];
  const float* vt   = (const float*)d_in[14];
  const float* Wfc  = (const float*)d_in[15];
  const float* bfc  = (const float*)d_in[16];
  float* out = (float*)d_out;

  char* ws = (char*)d_ws;
  size_t off = 0;
  bf16* encWF   = (bf16*)(ws + off); off += (size_t)48*8*64*8*sizeof(bf16);
  bf16* wtEncF  = (bf16*)(ws + off); off += (size_t)16*8*64*8*sizeof(bf16);
  bf16* wtDec   = (bf16*)(ws + off); off += (size_t)256*256*sizeof(bf16);
  bf16* whhD    = (bf16*)(ws + off); off += (size_t)768*256*sizeof(bf16);
  bf16* wihPD   = (bf16*)(ws + off); off += (size_t)768*288*sizeof(bf16);
  float* treprs = (float*)(ws + off); off += (size_t)B_TOT*T_LEN*3*sizeof(float);
  float* h_enc  = (float*)(ws + off); off += (size_t)B_TOT*H_DIM*sizeof(float);
  unsigned char* eo8 = (unsigned char*)(ws + off); off += (size_t)B_TOT*T_LEN*H_DIM;
  unsigned char* ep8 = (unsigned char*)(ws + off); off += (size_t)B_TOT*T_LEN*H_DIM;

  if (ws_size < off) return;

  convert_kernel<<<(768*288 + 255)/256, 256, 0, stream>>>(
      eWhh, Wt, dWhh, dWih, encWF, wtEncF, wtDec, whhD, wihPD);
  agent_attn_kernel<<<B_TOT*T_LEN/256, 256, 0, stream>>>(x, Wa, ba, va, treprs);
  encoder_kernel<<<B_TOT/4, 512, 0, stream>>>(encWF, eWih, ebih, ebhh,
                                              treprs, eo8, h_enc);
  proj_kernel<<<B_TOT*T_LEN/64, 256, 0, stream>>>(eo8, wtEncF, ep8);
  decoder_kernel<<<B_TOT/2, 512, 0, stream>>>(x, wtDec, bt, vt, wihPD, whhD,
                                              dbih, dbhh, Wfc, bfc, eo8, ep8,
                                              h_enc, out);
}